// Round 8
// baseline (461.028 us; speedup 1.0000x reference)
//
#include <hip/hip_runtime.h>
#include <hip/hip_fp16.h>
#include <math.h>

#define NH     16
#define HD     64
#define S_LEN  2048
#define THD_   1024
// exp(s*0.125) = exp2(s * 0.125 * log2(e))
#define SCALE_LOG2E 0.18033688011112042f

typedef __fp16 f16x8 __attribute__((ext_vector_type(8)));
typedef __fp16 f16x4 __attribute__((ext_vector_type(4)));
typedef __fp16 f16x2 __attribute__((ext_vector_type(2)));
typedef float  f32x4 __attribute__((ext_vector_type(4)));

// ws layout (half-elements; total 41,943,040 B, proven safe):
//   region A @ 0        : q_h  8,388,608   [b][comp][h][s][hd]  (PRE-SCALED by SCALE_LOG2E)
//   region B @ 8388608  : k_h  8,388,608   same layout (unscaled)
//   region C @ 16777216 : vt_h 4,194,304   [b][h][hd][s]
// time-shared:
//   WqT fp16 @ B[0:2097152)        (dead once q-GEMM done; k-GEMM overwrites)
//   WkT fp16 @ C[0:2097152)        (dead once k-GEMM done; v-GEMM overwrites)
//   rope tab fp32[2048][32][2] @ C[2097152:2359296) (dead before v-GEMM)
//   WoT @ A[0:1048576), gn_h @ A[1048576:5242880)   (A dead after attn)

// ---------------------------------------------------------------------------
// Shared weight-transpose body: W[k][n] fp32 -> WT[n][k] fp16.
// ---------------------------------------------------------------------------
__device__ inline void wt_body(const float* __restrict__ W,
                               __half* __restrict__ WT, int id, int nmask,
                               int nshift) {
  int n = id & nmask;
  int k8 = (id >> nshift) * 8;
  int N = nmask + 1;
  f16x8 h;
#pragma unroll
  for (int j = 0; j < 8; ++j)
    h[j] = (__fp16)W[(size_t)(k8 + j) * N + n];
  *(f16x8*)(WT + (size_t)n * 1024 + k8) = h;
}

// ---------------------------------------------------------------------------
// Fused prep: blocks [0,1024) transpose Wq; [1024,2048) transpose Wk;
// [2048,2304) fill the RoPE cos/sin table tab[s][p] (2048 x 32).
// ---------------------------------------------------------------------------
__global__ __launch_bounds__(256) void prep_kernel(
    const float* __restrict__ Wq, const float* __restrict__ Wk,
    __half* __restrict__ WqT, __half* __restrict__ WkT,
    float2* __restrict__ tab) {
  int bid = blockIdx.x;
  int t = threadIdx.x;
  if (bid < 1024) {
    wt_body(Wq, WqT, bid * 256 + t, 2047, 11);
  } else if (bid < 2048) {
    wt_body(Wk, WkT, (bid - 1024) * 256 + t, 2047, 11);
  } else {
    int id = (bid - 2048) * 256 + t;  // 65536
    int p = id & 31;
    int s = id >> 5;
    float inv = expf(-0.28782313662425574f * (float)p);
    float sn, cs;
    sincosf((float)s * inv, &sn, &cs);
    tab[id] = make_float2(cs, sn);
  }
}

// ---------------------------------------------------------------------------
// fp16 MFMA GEMM: C = A(4096 x 1024) * B(1024 x N). 128m x 64n tile, BK=64.
// 4 waves; wave w computes rows [w*32, w*32+32) x all 64 cols.  R7 lesson:
// this 1024-block grid (4 blocks/CU) beats a 128x128 tile at 512 blocks by
// ~22us/dispatch -- the pipeline is latency-bound; TLP wins over intensity.
// MODE 0: A = x fp32 (cast in staging), B = WT fp16; fused-RoPE epilogue
// MODE 1: MODE 0 + output scaled by SCALE_LOG2E (q path)
// MODE 2: A = x fp32, B = raw Wv fp32 column gather; fp16 to vt [b][h][hd][s]
// MODE 3: A = gn_h fp16, B = WoT fp16; epilogue fp32 row-major to d_out
// ---------------------------------------------------------------------------
template <int MODE>
__global__ __launch_bounds__(256) void mfma_gemm(const void* __restrict__ Ap,
                                                 const void* __restrict__ Bp,
                                                 void* __restrict__ Cp,
                                                 const float2* __restrict__ tab) {
  __shared__ __fp16 As[128][72];
  __shared__ __fp16 Bs[64][72];
  const int t = threadIdx.x;
  const int w = t >> 6, lane = t & 63;
  const int quad = lane >> 4, lqi = lane & 15;
  const int wm = w * 32;
  const int n0 = blockIdx.x * 64, m0 = blockIdx.y * 128;

  f32x4 acc[2][4];
#pragma unroll
  for (int mt = 0; mt < 2; ++mt)
#pragma unroll
    for (int nt = 0; nt < 4; ++nt) acc[mt][nt] = (f32x4){0.f, 0.f, 0.f, 0.f};

  const int srow = t >> 3;         // staging row base (0..31)
  const int sc8 = (t & 7) * 8;     // staging col (halves)
  const int gn_ = t & 63;          // gather: n within tile
  const int gk0 = (t >> 6) * 8;    // gather: k base (0,8,16,24)

  for (int k0 = 0; k0 < 1024; k0 += 64) {
    if (k0) __syncthreads();
    // ---- A staging ----
    if (MODE == 3) {
      const __half* A16 = (const __half*)Ap;
#pragma unroll
      for (int p = 0; p < 4; ++p) {
        int row = srow + 32 * p;
        *(f16x8*)&As[row][sc8] =
            *(const f16x8*)(A16 + (size_t)(m0 + row) * 1024 + k0 + sc8);
      }
    } else {
      const float* A32 = (const float*)Ap;
#pragma unroll
      for (int p = 0; p < 4; ++p) {
        int row = srow + 32 * p;
        const float* src = A32 + (size_t)(m0 + row) * 1024 + k0 + sc8;
        float4 u = *(const float4*)src;
        float4 v = *(const float4*)(src + 4);
        f16x8 h;
        h[0] = (__fp16)u.x; h[1] = (__fp16)u.y;
        h[2] = (__fp16)u.z; h[3] = (__fp16)u.w;
        h[4] = (__fp16)v.x; h[5] = (__fp16)v.y;
        h[6] = (__fp16)v.z; h[7] = (__fp16)v.w;
        *(f16x8*)&As[row][sc8] = h;
      }
    }
    // ---- B staging ----
    if (MODE == 2) {
      const float* B32 = (const float*)Bp;  // Wv row-major [k][1024]
#pragma unroll
      for (int p = 0; p < 2; ++p) {
        int kc = gk0 + 32 * p;
        f16x8 h;
#pragma unroll
        for (int j = 0; j < 8; ++j)
          h[j] = (__fp16)B32[(size_t)(k0 + kc + j) * 1024 + n0 + gn_];
        *(f16x8*)&Bs[gn_][kc] = h;
      }
    } else {
      const __half* B16 = (const __half*)Bp;  // WT [n][k]
      if (srow < 32) {
#pragma unroll
        for (int p = 0; p < 2; ++p) {
          int row = srow + 32 * p;
          *(f16x8*)&Bs[row][sc8] =
              *(const f16x8*)(B16 + (size_t)(n0 + row) * 1024 + k0 + sc8);
        }
      }
    }
    __syncthreads();
    // ---- MFMA ----
#pragma unroll
    for (int ks = 0; ks < 2; ++ks) {
      f16x8 af[2], bf[4];
#pragma unroll
      for (int mt = 0; mt < 2; ++mt)
        af[mt] = *(const f16x8*)&As[wm + mt * 16 + lqi][ks * 32 + quad * 8];
#pragma unroll
      for (int nt = 0; nt < 4; ++nt)
        bf[nt] = *(const f16x8*)&Bs[nt * 16 + lqi][ks * 32 + quad * 8];
#pragma unroll
      for (int mt = 0; mt < 2; ++mt)
#pragma unroll
        for (int nt = 0; nt < 4; ++nt)
          acc[mt][nt] = __builtin_amdgcn_mfma_f32_16x16x32_f16(
              af[mt], bf[nt], acc[mt][nt], 0, 0, 0);
    }
  }

  // ---- epilogue ----
  const int b = m0 >> 11;
  const int s0 = (m0 & 2047) + wm + quad * 4;
  if (MODE == 0 || MODE == 1) {
    __half* dst = (__half*)Cp;
    const int comp = n0 >> 10, hh = (n0 >> 6) & 15;
    __half* base = dst + ((size_t)(b * 2 + comp) * NH + hh) * (size_t)S_LEN * HD;
#pragma unroll
    for (int nt = 0; nt < 2; ++nt) {
      int p = nt * 16 + lqi;
#pragma unroll
      for (int mt = 0; mt < 2; ++mt) {
#pragma unroll
        for (int i = 0; i < 4; ++i) {
          int s = s0 + mt * 16 + i;
          float2 cs = tab[s * 32 + p];
          float x1 = acc[mt][nt][i], x2 = acc[mt][nt + 2][i];
          float y1 = x1 * cs.x - x2 * cs.y;
          float y2 = x2 * cs.x + x1 * cs.y;
          if (MODE == 1) { y1 *= SCALE_LOG2E; y2 *= SCALE_LOG2E; }
          base[(size_t)s * HD + p] = __float2half(y1);
          base[(size_t)s * HD + p + 32] = __float2half(y2);
        }
      }
    }
  } else if (MODE == 2) {
    __half* vt = (__half*)Cp;
    const int hh = n0 >> 6;
#pragma unroll
    for (int nt = 0; nt < 4; ++nt) {
      int hd = nt * 16 + lqi;
      __half* base = vt + (((size_t)b * NH + hh) * HD + hd) * S_LEN;
#pragma unroll
      for (int mt = 0; mt < 2; ++mt) {
        f16x4 hv;
#pragma unroll
        for (int i = 0; i < 4; ++i) hv[i] = (__fp16)acc[mt][nt][i];
        *(f16x4*)(base + s0 + mt * 16) = hv;
      }
    }
  } else {
    float* Co = (float*)Cp;
#pragma unroll
    for (int mt = 0; mt < 2; ++mt)
#pragma unroll
      for (int i = 0; i < 4; ++i) {
        int m = m0 + wm + mt * 16 + quad * 4 + i;
#pragma unroll
        for (int nt = 0; nt < 4; ++nt)
          Co[(size_t)m * 1024 + n0 + nt * 16 + lqi] = acc[mt][nt][i];
      }
  }
}

// ---------------------------------------------------------------------------
// Differential attention, R11: OCCUPANCY SPLIT. Evidence: attn pinned at
// 108.5us across two very different inner loops (R7/R9); Occupancy 20% =
// 8 waves/CU (grid 512 = exactly 2 blocks/CU); ~75% of per-kt wall time is
// unaccounted latency stall; and R7's GEMM experiment proved this pipeline
// loses when blocks/CU drops.  So: 64-query blocks (qt 0..31, grid 1024 =
// 4 blocks/CU), each wave owns 16 queries (nt dim removed).  To fit 4
// blocks/CU: V single-buffered (8KB) -- ALL V fragments are front-loaded to
// registers before barrier-1 each kt; K stays double-buffered (32KB).
// LDS 40KB, __launch_bounds__(256,4).  2 barriers/kt (count proven
// non-critical in R9).  Register-P full-rate x32 PV via custom key
// enumeration retained; scale folded into q.
// ---------------------------------------------------------------------------
__global__ __launch_bounds__(256, 4) void attn_kernel(
    const __half* __restrict__ q_h, const __half* __restrict__ k_h,
    const __half* __restrict__ vt_h, float* __restrict__ out,
    const float* __restrict__ lq1, const float* __restrict__ lk1,
    const float* __restrict__ lq2, const float* __restrict__ lk2,
    const float* __restrict__ lam_init_p) {
  // K: 16 chunks x 512 halves, chunk = str*8 + mt*2 + ks, addr lane*8.
  // V: [hd 0..63][key 0..63], XOR-swizzled 16B slots within each 128B row.
  __shared__ __half Ks[2][16][512];      // 32 KB (double-buffered)
  __shared__ __half Vs[64][64];          // 8 KB (single-buffered)

  const int t = threadIdx.x;
  const int w = t >> 6, lane = t & 63;
  const int quad = lane >> 4, lqi = lane & 15;
  const int r7 = lane & 7;
  const int qt = blockIdx.x;   // 0..31 (64-query tiles)
  const int bh = blockIdx.y;   // 0..31
  const int b = bh >> 4, h = bh & 15;

  const size_t c1 = ((size_t)(b * 2 + 0) * NH + h) * (size_t)S_LEN * HD;
  const size_t c2 = ((size_t)(b * 2 + 1) * NH + h) * (size_t)S_LEN * HD;
  const size_t vtb = ((size_t)b * NH + h) * (size_t)HD * S_LEN;
  const int q0 = qt * 64 + w * 16;   // wave's 16 queries

  f16x8 qf[2][2];  // [stream][ks]; q pre-scaled by SCALE_LOG2E
#pragma unroll
  for (int ks = 0; ks < 2; ++ks) {
    size_t a = (size_t)(q0 + lqi) * HD + ks * 32 + quad * 8;
    qf[0][ks] = *(const f16x8*)(q_h + c1 + a);
    qf[1][ks] = *(const f16x8*)(q_h + c2 + a);
  }

  f32x4 O[2][4];  // [stream][hd-chunk]
#pragma unroll
  for (int s = 0; s < 2; ++s)
#pragma unroll
    for (int hm = 0; hm < 4; ++hm) O[s][hm] = (f32x4){0.f, 0.f, 0.f, 0.f};
  float lsum[2] = {0.f, 0.f};

  // staging: 24 chunks (16 K + 8 V); wave w owns c = w + ci*4, ci in [0,6)
  auto k_src = [&](int c, int k0) -> const __half* {
    if (c < 16) {
      int str = c >> 3, mt = (c >> 1) & 3, ks = c & 1;
      return k_h + (str ? c2 : c1) + (size_t)(k0 + mt * 16 + lqi) * HD +
             ks * 32 + quad * 8;
    }
    int cc = c - 16;  // V chunk: rows [cc*8, cc*8+8), 64 keys
    return vt_h + vtb + (size_t)(cc * 8 + (lane >> 3)) * S_LEN + k0 +
           (lane & 7) * 8;
  };
  auto lds_dst = [&](int c, int buf) -> __half* {
    if (c < 16) return &Ks[buf][c][lane * 8];
    int cc = c - 16;
    int row = cc * 8 + (lane >> 3);
    int col = ((lane & 7) ^ (lane >> 3)) * 8;  // XOR-swizzled 16B slot
    return &Vs[row][col];
  };

  f16x8 r[6];
#pragma unroll
  for (int ci = 0; ci < 6; ++ci) r[ci] = *(const f16x8*)k_src(w + ci * 4, 0);
#pragma unroll
  for (int ci = 0; ci < 6; ++ci) *(f16x8*)lds_dst(w + ci * 4, 0) = r[ci];
  __syncthreads();

  for (int kt = 0; kt < 32; ++kt) {
    const int cur = kt & 1;
    // ---- 1) front-load ALL V fragments (permuted key order, swizzled) ----
    f16x8 vf[2][4];
#pragma unroll
    for (int g = 0; g < 2; ++g)
#pragma unroll
      for (int hm = 0; hm < 4; ++hm) {
        const __half* vrow = &Vs[hm * 16 + lqi][0];
        int s0 = (g * 4 + (quad >> 1)) ^ r7;      // keys g*32 + quad*4 ..
        int s1 = (g * 4 + 2 + (quad >> 1)) ^ r7;  // keys g*32+16 + quad*4 ..
        union { f16x8 v8; f16x4 v4[2]; } u;
        u.v4[0] = *(const f16x4*)(vrow + s0 * 8 + (quad & 1) * 4);
        u.v4[1] = *(const f16x4*)(vrow + s1 * 8 + (quad & 1) * 4);
        vf[g][hm] = u.v8;
      }
    __syncthreads();  // barrier-1: all V reads complete; Vs may be rewritten

    // ---- 2) issue next-tile global prefetch (lands during compute) ----
    if (kt < 31) {
#pragma unroll
      for (int ci = 0; ci < 6; ++ci)
        r[ci] = *(const f16x8*)k_src(w + ci * 4, (kt + 1) * 64);
    }

    // ---- 3) scores + exp + register-P PV ----
#pragma unroll
    for (int g = 0; g < 2; ++g) {  // 32-key groups (score tiles 2g, 2g+1)
#pragma unroll
      for (int str = 0; str < 2; ++str) {
        f16x8 kf00 = *(const f16x8*)&Ks[cur][str * 8 + g * 4 + 0][lane * 8];
        f16x8 kf01 = *(const f16x8*)&Ks[cur][str * 8 + g * 4 + 1][lane * 8];
        f16x8 kf10 = *(const f16x8*)&Ks[cur][str * 8 + g * 4 + 2][lane * 8];
        f16x8 kf11 = *(const f16x8*)&Ks[cur][str * 8 + g * 4 + 3][lane * 8];
        f32x4 sa = (f32x4){0.f, 0.f, 0.f, 0.f};
        f32x4 sb = (f32x4){0.f, 0.f, 0.f, 0.f};
        sa = __builtin_amdgcn_mfma_f32_16x16x32_f16(kf00, qf[str][0], sa,
                                                    0, 0, 0);
        sa = __builtin_amdgcn_mfma_f32_16x16x32_f16(kf01, qf[str][1], sa,
                                                    0, 0, 0);
        sb = __builtin_amdgcn_mfma_f32_16x16x32_f16(kf10, qf[str][0], sb,
                                                    0, 0, 0);
        sb = __builtin_amdgcn_mfma_f32_16x16x32_f16(kf11, qf[str][1], sb,
                                                    0, 0, 0);
        float ea0 = __builtin_amdgcn_exp2f(sa[0]);
        float ea1 = __builtin_amdgcn_exp2f(sa[1]);
        float ea2 = __builtin_amdgcn_exp2f(sa[2]);
        float ea3 = __builtin_amdgcn_exp2f(sa[3]);
        float eb0 = __builtin_amdgcn_exp2f(sb[0]);
        float eb1 = __builtin_amdgcn_exp2f(sb[1]);
        float eb2 = __builtin_amdgcn_exp2f(sb[2]);
        float eb3 = __builtin_amdgcn_exp2f(sb[3]);
        lsum[str] += ((ea0 + ea1) + (ea2 + ea3)) +
                     ((eb0 + eb1) + (eb2 + eb3));
        union { f16x8 v; f16x2 h2[4]; } pu;
        pu.h2[0] = __builtin_amdgcn_cvt_pkrtz(ea0, ea1);
        pu.h2[1] = __builtin_amdgcn_cvt_pkrtz(ea2, ea3);
        pu.h2[2] = __builtin_amdgcn_cvt_pkrtz(eb0, eb1);
        pu.h2[3] = __builtin_amdgcn_cvt_pkrtz(eb2, eb3);
        // PV: full-rate x32 MFMAs, P fragment straight from registers
#pragma unroll
        for (int hm = 0; hm < 4; ++hm)
          O[str][hm] = __builtin_amdgcn_mfma_f32_16x16x32_f16(
              vf[g][hm], pu.v, O[str][hm], 0, 0, 0);
      }
    }

    // ---- 4) stage next tile: K -> Ks[cur^1], V -> Vs ----
    if (kt < 31) {
#pragma unroll
      for (int ci = 0; ci < 6; ++ci)
        *(f16x8*)lds_dst(w + ci * 4, cur ^ 1) = r[ci];
    }
    __syncthreads();  // barrier-2: writes visible before next kt's reads
  }

  const float lam0 = lam_init_p[0];
  const float lam = expf(lq1[h] * lk1[h]) - expf(lq2[h] * lk2[h]) + lam0;
#pragma unroll
  for (int str = 0; str < 2; ++str) {
    float v = lsum[str];
    v += __shfl_xor(v, 16);
    v += __shfl_xor(v, 32);
    lsum[str] = v;
  }
  float il1 = 1.f / lsum[0];
  float il2 = lam / lsum[1];
  int q = q0 + lqi;
#pragma unroll
  for (int hm = 0; hm < 4; ++hm) {
    f32x4 o;
#pragma unroll
    for (int i = 0; i < 4; ++i)
      o[i] = O[0][hm][i] * il1 - O[1][hm][i] * il2;
    *(f32x4*)(out + ((size_t)(b * S_LEN + q)) * THD_ + h * HD + hm * 16 +
              quad * 4) = o;
  }
}

// ---------------------------------------------------------------------------
// Fused GroupNorm + Wo transpose. Blocks [0,16384): GroupNorm over 64-elem
// head groups (d_out fp32 -> gn_h fp16, * (1-lambda_init)); blocks
// [16384,16896): transpose Wo fp32 -> WoT fp16 [n][k].
// ---------------------------------------------------------------------------
__global__ __launch_bounds__(256) void gn_wt_kernel(
    const float* __restrict__ src, __half* __restrict__ dst,
    const float* __restrict__ gw, const float* __restrict__ gb,
    const float* __restrict__ lam_init_p, const float* __restrict__ Wo,
    __half* __restrict__ WoT) {
  if (blockIdx.x >= 16384) {
    wt_body(Wo, WoT, (blockIdx.x - 16384) * 256 + threadIdx.x, 1023, 10);
    return;
  }
  int g = blockIdx.x * 4 + (threadIdx.x >> 6);
  int lane = threadIdx.x & 63;
  float v = src[(size_t)g * 64 + lane];
  float s = v, sq = v * v;
#pragma unroll
  for (int off = 32; off; off >>= 1) {
    s += __shfl_xor(s, off);
    sq += __shfl_xor(sq, off);
  }
  float mean = s * (1.f / 64.f);
  float var = sq * (1.f / 64.f) - mean * mean;
  float rs = rsqrtf(var + 1e-5f);
  int h = g & 15;
  float w = gw[h * 64 + lane], bb = gb[h * 64 + lane];
  dst[(size_t)g * 64 + lane] =
      __float2half(((v - mean) * rs * w + bb) * (1.f - lam_init_p[0]));
}

// ---------------------------------------------------------------------------
extern "C" void kernel_launch(void* const* d_in, const int* in_sizes, int n_in,
                              void* d_out, int out_size, void* d_ws,
                              size_t ws_size, hipStream_t stream) {
  const float* x = (const float*)d_in[0];
  const float* Wq = (const float*)d_in[1];
  const float* Wk = (const float*)d_in[2];
  const float* Wv = (const float*)d_in[3];
  const float* Wo = (const float*)d_in[4];
  const float* lq1 = (const float*)d_in[5];
  const float* lk1 = (const float*)d_in[6];
  const float* lq2 = (const float*)d_in[7];
  const float* lk2 = (const float*)d_in[8];
  const float* lam_init = (const float*)d_in[9];
  const float* gnw = (const float*)d_in[10];
  const float* gnb = (const float*)d_in[11];
  float* out = (float*)d_out;

  __half* q_h = (__half*)d_ws;          // region A
  __half* k_h = q_h + 8388608;          // region B
  __half* vt_h = k_h + 8388608;         // region C
  __half* WqT = k_h;                    // B[0:2097152)  (dead after q-GEMM)
  __half* WkT = vt_h;                   // C[0:2097152)  (dead after k-GEMM)
  float2* tab = (float2*)(vt_h + 2097152);  // C[2097152:2359296) fp32 pairs
  __half* WoT = q_h;                    // A[0:1048576)  (q dead after attn)
  __half* gn_h = q_h + 1048576;         // A[1048576:5242880)

  dim3 blk(256);
  // fused prep: Wq/Wk transposes + rope table (1 dispatch)
  prep_kernel<<<2304, blk, 0, stream>>>(Wq, Wk, WqT, WkT, tab);
  // projections (64-wide tiles, R6 proven config); MODE 1 folds scale*log2e
  mfma_gemm<1><<<dim3(32, 32), blk, 0, stream>>>(x, WqT, q_h, tab);
  mfma_gemm<0><<<dim3(32, 32), blk, 0, stream>>>(x, WkT, k_h, tab);
  mfma_gemm<2><<<dim3(16, 32), blk, 0, stream>>>(x, Wv, vt_h, nullptr);
  // differential attention -> d_out (R11: 64-query blocks, 4 blocks/CU)
  attn_kernel<<<dim3(32, 32), blk, 0, stream>>>(q_h, k_h, vt_h, out, lq1, lk1,
                                                lq2, lk2, lam_init);
  // fused GroupNorm + Wo transpose (1 dispatch)
  gn_wt_kernel<<<16896, blk, 0, stream>>>(out, gn_h, gnw, gnb, lam_init, Wo,
                                          WoT);
  // output projection: gn_h @ WoT -> d_out
  mfma_gemm<3><<<dim3(16, 32), blk, 0, stream>>>(gn_h, WoT, out, nullptr);
}

// Round 12
// 354.738 us; speedup vs baseline: 1.2996x; 1.2996x over previous
//
#include <hip/hip_runtime.h>
#include <hip/hip_fp16.h>
#include <math.h>

#define NH     16
#define HD     64
#define S_LEN  2048
#define THD_   1024
// exp(s*0.125) = exp2(s * 0.125 * log2(e))
#define SCALE_LOG2E 0.18033688011112042f

typedef __fp16 f16x8 __attribute__((ext_vector_type(8)));
typedef __fp16 f16x4 __attribute__((ext_vector_type(4)));
typedef __fp16 f16x2 __attribute__((ext_vector_type(2)));
typedef float  f32x4 __attribute__((ext_vector_type(4)));

// ws layout (half-elements; total 41,943,040 B, proven safe):
//   region A @ 0        : q_h  8,388,608   [b][comp][h][s][hd]  (PRE-SCALED by SCALE_LOG2E)
//   region B @ 8388608  : k_h  8,388,608   same layout (unscaled)
//   region C @ 16777216 : vt_h 4,194,304   [b][h][hd][s]
// time-shared:
//   WqT fp16 @ B[0:2097152)        (dead once q-GEMM done; k-GEMM overwrites)
//   WkT fp16 @ C[0:2097152)        (dead once k-GEMM done; v-GEMM overwrites)
//   rope tab fp32[2048][32][2] @ C[2097152:2359296) (dead before v-GEMM)
//   WoT @ A[0:1048576), gn_h @ A[1048576:5242880)   (A dead after attn)

// ---------------------------------------------------------------------------
// Shared weight-transpose body: W[k][n] fp32 -> WT[n][k] fp16.
// ---------------------------------------------------------------------------
__device__ inline void wt_body(const float* __restrict__ W,
                               __half* __restrict__ WT, int id, int nmask,
                               int nshift) {
  int n = id & nmask;
  int k8 = (id >> nshift) * 8;
  int N = nmask + 1;
  f16x8 h;
#pragma unroll
  for (int j = 0; j < 8; ++j)
    h[j] = (__fp16)W[(size_t)(k8 + j) * N + n];
  *(f16x8*)(WT + (size_t)n * 1024 + k8) = h;
}

// ---------------------------------------------------------------------------
// Fused prep: blocks [0,1024) transpose Wq; [1024,2048) transpose Wk;
// [2048,2304) fill the RoPE cos/sin table tab[s][p] (2048 x 32).
// ---------------------------------------------------------------------------
__global__ __launch_bounds__(256) void prep_kernel(
    const float* __restrict__ Wq, const float* __restrict__ Wk,
    __half* __restrict__ WqT, __half* __restrict__ WkT,
    float2* __restrict__ tab) {
  int bid = blockIdx.x;
  int t = threadIdx.x;
  if (bid < 1024) {
    wt_body(Wq, WqT, bid * 256 + t, 2047, 11);
  } else if (bid < 2048) {
    wt_body(Wk, WkT, (bid - 1024) * 256 + t, 2047, 11);
  } else {
    int id = (bid - 2048) * 256 + t;  // 65536
    int p = id & 31;
    int s = id >> 5;
    float inv = expf(-0.28782313662425574f * (float)p);
    float sn, cs;
    sincosf((float)s * inv, &sn, &cs);
    tab[id] = make_float2(cs, sn);
  }
}

// ---------------------------------------------------------------------------
// fp16 MFMA GEMM: C = A(4096 x 1024) * B(1024 x N). 128m x 64n tile, BK=64.
// 4 waves; wave w computes rows [w*32, w*32+32) x all 64 cols.  R7 lesson:
// this 1024-block grid (4 blocks/CU) beats a 128x128 tile at 512 blocks by
// ~22us/dispatch -- the pipeline is latency-bound; TLP wins over intensity.
// MODE 0: A = x fp32 (cast in staging), B = WT fp16; fused-RoPE epilogue
// MODE 1: MODE 0 + output scaled by SCALE_LOG2E (q path)
// MODE 2: A = x fp32, B = raw Wv fp32 column gather; fp16 to vt [b][h][hd][s]
// MODE 3: A = gn_h fp16, B = WoT fp16; epilogue fp32 row-major to d_out
// ---------------------------------------------------------------------------
template <int MODE>
__global__ __launch_bounds__(256) void mfma_gemm(const void* __restrict__ Ap,
                                                 const void* __restrict__ Bp,
                                                 void* __restrict__ Cp,
                                                 const float2* __restrict__ tab) {
  __shared__ __fp16 As[128][72];
  __shared__ __fp16 Bs[64][72];
  const int t = threadIdx.x;
  const int w = t >> 6, lane = t & 63;
  const int quad = lane >> 4, lqi = lane & 15;
  const int wm = w * 32;
  const int n0 = blockIdx.x * 64, m0 = blockIdx.y * 128;

  f32x4 acc[2][4];
#pragma unroll
  for (int mt = 0; mt < 2; ++mt)
#pragma unroll
    for (int nt = 0; nt < 4; ++nt) acc[mt][nt] = (f32x4){0.f, 0.f, 0.f, 0.f};

  const int srow = t >> 3;         // staging row base (0..31)
  const int sc8 = (t & 7) * 8;     // staging col (halves)
  const int gn_ = t & 63;          // gather: n within tile
  const int gk0 = (t >> 6) * 8;    // gather: k base (0,8,16,24)

  for (int k0 = 0; k0 < 1024; k0 += 64) {
    if (k0) __syncthreads();
    // ---- A staging ----
    if (MODE == 3) {
      const __half* A16 = (const __half*)Ap;
#pragma unroll
      for (int p = 0; p < 4; ++p) {
        int row = srow + 32 * p;
        *(f16x8*)&As[row][sc8] =
            *(const f16x8*)(A16 + (size_t)(m0 + row) * 1024 + k0 + sc8);
      }
    } else {
      const float* A32 = (const float*)Ap;
#pragma unroll
      for (int p = 0; p < 4; ++p) {
        int row = srow + 32 * p;
        const float* src = A32 + (size_t)(m0 + row) * 1024 + k0 + sc8;
        float4 u = *(const float4*)src;
        float4 v = *(const float4*)(src + 4);
        f16x8 h;
        h[0] = (__fp16)u.x; h[1] = (__fp16)u.y;
        h[2] = (__fp16)u.z; h[3] = (__fp16)u.w;
        h[4] = (__fp16)v.x; h[5] = (__fp16)v.y;
        h[6] = (__fp16)v.z; h[7] = (__fp16)v.w;
        *(f16x8*)&As[row][sc8] = h;
      }
    }
    // ---- B staging ----
    if (MODE == 2) {
      const float* B32 = (const float*)Bp;  // Wv row-major [k][1024]
#pragma unroll
      for (int p = 0; p < 2; ++p) {
        int kc = gk0 + 32 * p;
        f16x8 h;
#pragma unroll
        for (int j = 0; j < 8; ++j)
          h[j] = (__fp16)B32[(size_t)(k0 + kc + j) * 1024 + n0 + gn_];
        *(f16x8*)&Bs[gn_][kc] = h;
      }
    } else {
      const __half* B16 = (const __half*)Bp;  // WT [n][k]
      if (srow < 32) {
#pragma unroll
        for (int p = 0; p < 2; ++p) {
          int row = srow + 32 * p;
          *(f16x8*)&Bs[row][sc8] =
              *(const f16x8*)(B16 + (size_t)(n0 + row) * 1024 + k0 + sc8);
        }
      }
    }
    __syncthreads();
    // ---- MFMA ----
#pragma unroll
    for (int ks = 0; ks < 2; ++ks) {
      f16x8 af[2], bf[4];
#pragma unroll
      for (int mt = 0; mt < 2; ++mt)
        af[mt] = *(const f16x8*)&As[wm + mt * 16 + lqi][ks * 32 + quad * 8];
#pragma unroll
      for (int nt = 0; nt < 4; ++nt)
        bf[nt] = *(const f16x8*)&Bs[nt * 16 + lqi][ks * 32 + quad * 8];
#pragma unroll
      for (int mt = 0; mt < 2; ++mt)
#pragma unroll
        for (int nt = 0; nt < 4; ++nt)
          acc[mt][nt] = __builtin_amdgcn_mfma_f32_16x16x32_f16(
              af[mt], bf[nt], acc[mt][nt], 0, 0, 0);
    }
  }

  // ---- epilogue ----
  const int b = m0 >> 11;
  const int s0 = (m0 & 2047) + wm + quad * 4;
  if (MODE == 0 || MODE == 1) {
    __half* dst = (__half*)Cp;
    const int comp = n0 >> 10, hh = (n0 >> 6) & 15;
    __half* base = dst + ((size_t)(b * 2 + comp) * NH + hh) * (size_t)S_LEN * HD;
#pragma unroll
    for (int nt = 0; nt < 2; ++nt) {
      int p = nt * 16 + lqi;
#pragma unroll
      for (int mt = 0; mt < 2; ++mt) {
#pragma unroll
        for (int i = 0; i < 4; ++i) {
          int s = s0 + mt * 16 + i;
          float2 cs = tab[s * 32 + p];
          float x1 = acc[mt][nt][i], x2 = acc[mt][nt + 2][i];
          float y1 = x1 * cs.x - x2 * cs.y;
          float y2 = x2 * cs.x + x1 * cs.y;
          if (MODE == 1) { y1 *= SCALE_LOG2E; y2 *= SCALE_LOG2E; }
          base[(size_t)s * HD + p] = __float2half(y1);
          base[(size_t)s * HD + p + 32] = __float2half(y2);
        }
      }
    }
  } else if (MODE == 2) {
    __half* vt = (__half*)Cp;
    const int hh = n0 >> 6;
#pragma unroll
    for (int nt = 0; nt < 4; ++nt) {
      int hd = nt * 16 + lqi;
      __half* base = vt + (((size_t)b * NH + hh) * HD + hd) * S_LEN;
#pragma unroll
      for (int mt = 0; mt < 2; ++mt) {
        f16x4 hv;
#pragma unroll
        for (int i = 0; i < 4; ++i) hv[i] = (__fp16)acc[mt][nt][i];
        *(f16x4*)(base + s0 + mt * 16) = hv;
      }
    }
  } else {
    float* Co = (float*)Cp;
#pragma unroll
    for (int mt = 0; mt < 2; ++mt)
#pragma unroll
      for (int i = 0; i < 4; ++i) {
        int m = m0 + wm + mt * 16 + quad * 4 + i;
#pragma unroll
        for (int nt = 0; nt < 4; ++nt)
          Co[(size_t)m * 1024 + n0 + nt * 16 + lqi] = acc[mt][nt][i];
      }
  }
}

// ---------------------------------------------------------------------------
// Differential attention, R12: 512-THREAD BLOCKS, SAME TILING. Post-mortem
// chain: attn pinned at 108.5us across two inner-loop designs (R7/R9);
// R11 (more 64-query blocks) doubled occupancy but quadrupled L2-miss
// traffic (FETCH 109->438MB) and regressed to 231us => TLP helps only at
// constant traffic.  This kernel keeps the R6 tiling exactly (grid 16x32,
// each block owns 128 queries, reads full KV once => FETCH ~109MB) but runs
// 8 waves/block; each wave owns 16 queries (R11's verified per-wave math),
// 3 staging chunks/wave.  LDS 48KB unchanged -> 2 blocks/CU, now 16
// waves/CU = 4 waves/SIMD (was 2): anti-phased waves fill the MFMA and VALU
// pipes that the serial QK->exp->PV chain leaves idle at 2 waves/SIMD.
// Register-P full-rate x32 PV via custom key enumeration; one barrier/kt;
// scale folded into q.  __launch_bounds__(512,4) = 2 blocks/CU.
// ---------------------------------------------------------------------------
__global__ __launch_bounds__(512, 4) void attn_kernel(
    const __half* __restrict__ q_h, const __half* __restrict__ k_h,
    const __half* __restrict__ vt_h, float* __restrict__ out,
    const float* __restrict__ lq1, const float* __restrict__ lk1,
    const float* __restrict__ lq2, const float* __restrict__ lk2,
    const float* __restrict__ lam_init_p) {
  // K: 16 chunks x 512 halves, chunk = str*8 + mt*2 + ks, addr lane*8.
  // V: [hd 0..63][key 0..63], XOR-swizzled 16B slots within each 128B row.
  __shared__ __half Ks[2][16][512];      // 32 KB
  __shared__ __half Vs[2][64][64];       // 16 KB

  const int t = threadIdx.x;
  const int w = t >> 6, lane = t & 63;   // w in 0..7
  const int quad = lane >> 4, lqi = lane & 15;
  const int r7 = lane & 7;
  const int qt = blockIdx.x;   // 0..15 (128-query tiles)
  const int bh = blockIdx.y;   // 0..31
  const int b = bh >> 4, h = bh & 15;

  const size_t c1 = ((size_t)(b * 2 + 0) * NH + h) * (size_t)S_LEN * HD;
  const size_t c2 = ((size_t)(b * 2 + 1) * NH + h) * (size_t)S_LEN * HD;
  const size_t vtb = ((size_t)b * NH + h) * (size_t)HD * S_LEN;
  const int q0 = qt * 128 + w * 16;   // wave's 16 queries

  f16x8 qf[2][2];  // [stream][ks]; q pre-scaled by SCALE_LOG2E
#pragma unroll
  for (int ks = 0; ks < 2; ++ks) {
    size_t a = (size_t)(q0 + lqi) * HD + ks * 32 + quad * 8;
    qf[0][ks] = *(const f16x8*)(q_h + c1 + a);
    qf[1][ks] = *(const f16x8*)(q_h + c2 + a);
  }

  f32x4 O[2][4];  // [stream][hd-chunk]
#pragma unroll
  for (int s = 0; s < 2; ++s)
#pragma unroll
    for (int hm = 0; hm < 4; ++hm) O[s][hm] = (f32x4){0.f, 0.f, 0.f, 0.f};
  float lsum[2] = {0.f, 0.f};

  // staging: 24 chunks (16 K + 8 V); wave w owns c = w + ci*8, ci in [0,3)
  auto k_src = [&](int c, int k0) -> const __half* {
    if (c < 16) {
      int str = c >> 3, mt = (c >> 1) & 3, ks = c & 1;
      return k_h + (str ? c2 : c1) + (size_t)(k0 + mt * 16 + lqi) * HD +
             ks * 32 + quad * 8;
    }
    int cc = c - 16;  // V chunk: rows [cc*8, cc*8+8), 64 keys
    return vt_h + vtb + (size_t)(cc * 8 + (lane >> 3)) * S_LEN + k0 +
           (lane & 7) * 8;
  };
  auto lds_dst = [&](int c, int buf) -> __half* {
    if (c < 16) return &Ks[buf][c][lane * 8];
    int cc = c - 16;
    int row = cc * 8 + (lane >> 3);
    int col = ((lane & 7) ^ (lane >> 3)) * 8;  // XOR-swizzled 16B slot
    return &Vs[buf][row][col];
  };

  f16x8 r[3];
#pragma unroll
  for (int ci = 0; ci < 3; ++ci) r[ci] = *(const f16x8*)k_src(w + ci * 8, 0);
#pragma unroll
  for (int ci = 0; ci < 3; ++ci) *(f16x8*)lds_dst(w + ci * 8, 0) = r[ci];
  __syncthreads();

  for (int kt = 0; kt < 32; ++kt) {
    const int cur = kt & 1;
    if (kt < 31) {  // issue next-tile global loads; land during compute
#pragma unroll
      for (int ci = 0; ci < 3; ++ci)
        r[ci] = *(const f16x8*)k_src(w + ci * 8, (kt + 1) * 64);
    }

#pragma unroll
    for (int g = 0; g < 2; ++g) {  // 32-key groups (score tiles 2g, 2g+1)
      // ---- V fragments in permuted key order (2 b64 each, swizzle-read) ---
      f16x8 vf[4];
#pragma unroll
      for (int hm = 0; hm < 4; ++hm) {
        const __half* vrow = &Vs[cur][hm * 16 + lqi][0];
        int s0 = (g * 4 + (quad >> 1)) ^ r7;      // keys g*32 + quad*4 ..
        int s1 = (g * 4 + 2 + (quad >> 1)) ^ r7;  // keys g*32+16 + quad*4 ..
        union { f16x8 v8; f16x4 v4[2]; } u;
        u.v4[0] = *(const f16x4*)(vrow + s0 * 8 + (quad & 1) * 4);
        u.v4[1] = *(const f16x4*)(vrow + s1 * 8 + (quad & 1) * 4);
        vf[hm] = u.v8;
      }
      // ---- scores + exp + register-P PV ----
#pragma unroll
      for (int str = 0; str < 2; ++str) {
        f16x8 kf00 = *(const f16x8*)&Ks[cur][str * 8 + g * 4 + 0][lane * 8];
        f16x8 kf01 = *(const f16x8*)&Ks[cur][str * 8 + g * 4 + 1][lane * 8];
        f16x8 kf10 = *(const f16x8*)&Ks[cur][str * 8 + g * 4 + 2][lane * 8];
        f16x8 kf11 = *(const f16x8*)&Ks[cur][str * 8 + g * 4 + 3][lane * 8];
        f32x4 sa = (f32x4){0.f, 0.f, 0.f, 0.f};
        f32x4 sb = (f32x4){0.f, 0.f, 0.f, 0.f};
        sa = __builtin_amdgcn_mfma_f32_16x16x32_f16(kf00, qf[str][0], sa,
                                                    0, 0, 0);
        sa = __builtin_amdgcn_mfma_f32_16x16x32_f16(kf01, qf[str][1], sa,
                                                    0, 0, 0);
        sb = __builtin_amdgcn_mfma_f32_16x16x32_f16(kf10, qf[str][0], sb,
                                                    0, 0, 0);
        sb = __builtin_amdgcn_mfma_f32_16x16x32_f16(kf11, qf[str][1], sb,
                                                    0, 0, 0);
        float ea0 = __builtin_amdgcn_exp2f(sa[0]);
        float ea1 = __builtin_amdgcn_exp2f(sa[1]);
        float ea2 = __builtin_amdgcn_exp2f(sa[2]);
        float ea3 = __builtin_amdgcn_exp2f(sa[3]);
        float eb0 = __builtin_amdgcn_exp2f(sb[0]);
        float eb1 = __builtin_amdgcn_exp2f(sb[1]);
        float eb2 = __builtin_amdgcn_exp2f(sb[2]);
        float eb3 = __builtin_amdgcn_exp2f(sb[3]);
        lsum[str] += ((ea0 + ea1) + (ea2 + ea3)) +
                     ((eb0 + eb1) + (eb2 + eb3));
        union { f16x8 v; f16x2 h2[4]; } pu;
        pu.h2[0] = __builtin_amdgcn_cvt_pkrtz(ea0, ea1);
        pu.h2[1] = __builtin_amdgcn_cvt_pkrtz(ea2, ea3);
        pu.h2[2] = __builtin_amdgcn_cvt_pkrtz(eb0, eb1);
        pu.h2[3] = __builtin_amdgcn_cvt_pkrtz(eb2, eb3);
        // PV: full-rate x32 MFMAs, P fragment straight from registers
#pragma unroll
        for (int hm = 0; hm < 4; ++hm)
          O[str][hm] = __builtin_amdgcn_mfma_f32_16x16x32_f16(
              vf[hm], pu.v, O[str][hm], 0, 0, 0);
      }
    }

    if (kt < 31) {  // stage next tile into the other buffer
#pragma unroll
      for (int ci = 0; ci < 3; ++ci)
        *(f16x8*)lds_dst(w + ci * 8, cur ^ 1) = r[ci];
      __syncthreads();
    }
  }

  const float lam0 = lam_init_p[0];
  const float lam = expf(lq1[h] * lk1[h]) - expf(lq2[h] * lk2[h]) + lam0;
#pragma unroll
  for (int str = 0; str < 2; ++str) {
    float v = lsum[str];
    v += __shfl_xor(v, 16);
    v += __shfl_xor(v, 32);
    lsum[str] = v;
  }
  float il1 = 1.f / lsum[0];
  float il2 = lam / lsum[1];
  int q = q0 + lqi;
#pragma unroll
  for (int hm = 0; hm < 4; ++hm) {
    f32x4 o;
#pragma unroll
    for (int i = 0; i < 4; ++i)
      o[i] = O[0][hm][i] * il1 - O[1][hm][i] * il2;
    *(f32x4*)(out + ((size_t)(b * S_LEN + q)) * THD_ + h * HD + hm * 16 +
              quad * 4) = o;
  }
}

// ---------------------------------------------------------------------------
// Fused GroupNorm + Wo transpose. Blocks [0,16384): GroupNorm over 64-elem
// head groups (d_out fp32 -> gn_h fp16, * (1-lambda_init)); blocks
// [16384,16896): transpose Wo fp32 -> WoT fp16 [n][k].
// ---------------------------------------------------------------------------
__global__ __launch_bounds__(256) void gn_wt_kernel(
    const float* __restrict__ src, __half* __restrict__ dst,
    const float* __restrict__ gw, const float* __restrict__ gb,
    const float* __restrict__ lam_init_p, const float* __restrict__ Wo,
    __half* __restrict__ WoT) {
  if (blockIdx.x >= 16384) {
    wt_body(Wo, WoT, (blockIdx.x - 16384) * 256 + threadIdx.x, 1023, 10);
    return;
  }
  int g = blockIdx.x * 4 + (threadIdx.x >> 6);
  int lane = threadIdx.x & 63;
  float v = src[(size_t)g * 64 + lane];
  float s = v, sq = v * v;
#pragma unroll
  for (int off = 32; off; off >>= 1) {
    s += __shfl_xor(s, off);
    sq += __shfl_xor(sq, off);
  }
  float mean = s * (1.f / 64.f);
  float var = sq * (1.f / 64.f) - mean * mean;
  float rs = rsqrtf(var + 1e-5f);
  int h = g & 15;
  float w = gw[h * 64 + lane], bb = gb[h * 64 + lane];
  dst[(size_t)g * 64 + lane] =
      __float2half(((v - mean) * rs * w + bb) * (1.f - lam_init_p[0]));
}

// ---------------------------------------------------------------------------
extern "C" void kernel_launch(void* const* d_in, const int* in_sizes, int n_in,
                              void* d_out, int out_size, void* d_ws,
                              size_t ws_size, hipStream_t stream) {
  const float* x = (const float*)d_in[0];
  const float* Wq = (const float*)d_in[1];
  const float* Wk = (const float*)d_in[2];
  const float* Wv = (const float*)d_in[3];
  const float* Wo = (const float*)d_in[4];
  const float* lq1 = (const float*)d_in[5];
  const float* lk1 = (const float*)d_in[6];
  const float* lq2 = (const float*)d_in[7];
  const float* lk2 = (const float*)d_in[8];
  const float* lam_init = (const float*)d_in[9];
  const float* gnw = (const float*)d_in[10];
  const float* gnb = (const float*)d_in[11];
  float* out = (float*)d_out;

  __half* q_h = (__half*)d_ws;          // region A
  __half* k_h = q_h + 8388608;          // region B
  __half* vt_h = k_h + 8388608;         // region C
  __half* WqT = k_h;                    // B[0:2097152)  (dead after q-GEMM)
  __half* WkT = vt_h;                   // C[0:2097152)  (dead after k-GEMM)
  float2* tab = (float2*)(vt_h + 2097152);  // C[2097152:2359296) fp32 pairs
  __half* WoT = q_h;                    // A[0:1048576)  (q dead after attn)
  __half* gn_h = q_h + 1048576;         // A[1048576:5242880)

  dim3 blk(256);
  // fused prep: Wq/Wk transposes + rope table (1 dispatch)
  prep_kernel<<<2304, blk, 0, stream>>>(Wq, Wk, WqT, WkT, tab);
  // projections (64-wide tiles, R6 proven config); MODE 1 folds scale*log2e
  mfma_gemm<1><<<dim3(32, 32), blk, 0, stream>>>(x, WqT, q_h, tab);
  mfma_gemm<0><<<dim3(32, 32), blk, 0, stream>>>(x, WkT, k_h, tab);
  mfma_gemm<2><<<dim3(16, 32), blk, 0, stream>>>(x, Wv, vt_h, nullptr);
  // differential attention -> d_out (R12: 8-wave blocks, same tiling/traffic)
  attn_kernel<<<dim3(16, 32), dim3(512), 0, stream>>>(q_h, k_h, vt_h, out,
                                                      lq1, lk1, lq2, lk2,
                                                      lam_init);
  // fused GroupNorm + Wo transpose (1 dispatch)
  gn_wt_kernel<<<16896, blk, 0, stream>>>(out, gn_h, gnw, gnb, lam_init, Wo,
                                          WoT);
  // output projection: gn_h @ WoT -> d_out
  mfma_gemm<3><<<dim3(16, 32), blk, 0, stream>>>(gn_h, WoT, out, nullptr);
}

// Round 13
// 319.385 us; speedup vs baseline: 1.4435x; 1.1107x over previous
//
#include <hip/hip_runtime.h>
#include <hip/hip_fp16.h>
#include <math.h>

#define NH     16
#define HD     64
#define S_LEN  2048
#define THD_   1024
// exp(s*0.125) = exp2(s * 0.125 * log2(e))
#define SCALE_LOG2E 0.18033688011112042f

typedef __fp16 f16x8 __attribute__((ext_vector_type(8)));
typedef __fp16 f16x4 __attribute__((ext_vector_type(4)));
typedef __fp16 f16x2 __attribute__((ext_vector_type(2)));
typedef float  f32x4 __attribute__((ext_vector_type(4)));

// ws layout (half-elements; total 41,943,040 B, proven safe):
//   region A @ 0        : q_h  8,388,608   [b][comp][h][s][hd]  (PRE-SCALED by SCALE_LOG2E)
//   region B @ 8388608  : k_h  8,388,608   same layout (unscaled)
//   region C @ 16777216 : vt_h 4,194,304   [b][h][hd][s]
// time-shared:
//   WqT fp16 @ B[0:2097152)        (dead once q-GEMM done; k-GEMM overwrites)
//   WkT fp16 @ C[0:2097152)        (dead once k-GEMM done; v-GEMM overwrites)
//   rope tab fp32[2048][32][2] @ C[2097152:2359296) (dead before v-GEMM)
//   WoT @ A[0:1048576), gn_h @ A[1048576:5242880)   (A dead after attn)

// ---------------------------------------------------------------------------
// Shared weight-transpose body: W[k][n] fp32 -> WT[n][k] fp16.
// ---------------------------------------------------------------------------
__device__ inline void wt_body(const float* __restrict__ W,
                               __half* __restrict__ WT, int id, int nmask,
                               int nshift) {
  int n = id & nmask;
  int k8 = (id >> nshift) * 8;
  int N = nmask + 1;
  f16x8 h;
#pragma unroll
  for (int j = 0; j < 8; ++j)
    h[j] = (__fp16)W[(size_t)(k8 + j) * N + n];
  *(f16x8*)(WT + (size_t)n * 1024 + k8) = h;
}

// ---------------------------------------------------------------------------
// Fused prep: blocks [0,1024) transpose Wq; [1024,2048) transpose Wk;
// [2048,2304) fill the RoPE cos/sin table tab[s][p] (2048 x 32).
// ---------------------------------------------------------------------------
__global__ __launch_bounds__(256) void prep_kernel(
    const float* __restrict__ Wq, const float* __restrict__ Wk,
    __half* __restrict__ WqT, __half* __restrict__ WkT,
    float2* __restrict__ tab) {
  int bid = blockIdx.x;
  int t = threadIdx.x;
  if (bid < 1024) {
    wt_body(Wq, WqT, bid * 256 + t, 2047, 11);
  } else if (bid < 2048) {
    wt_body(Wk, WkT, (bid - 1024) * 256 + t, 2047, 11);
  } else {
    int id = (bid - 2048) * 256 + t;  // 65536
    int p = id & 31;
    int s = id >> 5;
    float inv = expf(-0.28782313662425574f * (float)p);
    float sn, cs;
    sincosf((float)s * inv, &sn, &cs);
    tab[id] = make_float2(cs, sn);
  }
}

// ---------------------------------------------------------------------------
// fp16 MFMA GEMM: C = A(4096 x 1024) * B(1024 x N). 128m x 64n tile, BK=64.
// 4 waves; wave w computes rows [w*32, w*32+32) x all 64 cols.  R7 lesson:
// this 1024-block grid (4 blocks/CU) beats a 128x128 tile at 512 blocks by
// ~22us/dispatch -- the pipeline is latency-bound; TLP wins over intensity.
// MODE 0: A = x fp32 (cast in staging), B = WT fp16; fused-RoPE epilogue
// MODE 1: MODE 0 + output scaled by SCALE_LOG2E (q path)
// MODE 2: A = x fp32, B = raw Wv fp32 column gather; fp16 to vt [b][h][hd][s]
// MODE 3: A = gn_h fp16, B = WoT fp16; epilogue fp32 row-major to d_out
// ---------------------------------------------------------------------------
template <int MODE>
__global__ __launch_bounds__(256) void mfma_gemm(const void* __restrict__ Ap,
                                                 const void* __restrict__ Bp,
                                                 void* __restrict__ Cp,
                                                 const float2* __restrict__ tab) {
  __shared__ __fp16 As[128][72];
  __shared__ __fp16 Bs[64][72];
  const int t = threadIdx.x;
  const int w = t >> 6, lane = t & 63;
  const int quad = lane >> 4, lqi = lane & 15;
  const int wm = w * 32;
  const int n0 = blockIdx.x * 64, m0 = blockIdx.y * 128;

  f32x4 acc[2][4];
#pragma unroll
  for (int mt = 0; mt < 2; ++mt)
#pragma unroll
    for (int nt = 0; nt < 4; ++nt) acc[mt][nt] = (f32x4){0.f, 0.f, 0.f, 0.f};

  const int srow = t >> 3;         // staging row base (0..31)
  const int sc8 = (t & 7) * 8;     // staging col (halves)
  const int gn_ = t & 63;          // gather: n within tile
  const int gk0 = (t >> 6) * 8;    // gather: k base (0,8,16,24)

  for (int k0 = 0; k0 < 1024; k0 += 64) {
    if (k0) __syncthreads();
    // ---- A staging ----
    if (MODE == 3) {
      const __half* A16 = (const __half*)Ap;
#pragma unroll
      for (int p = 0; p < 4; ++p) {
        int row = srow + 32 * p;
        *(f16x8*)&As[row][sc8] =
            *(const f16x8*)(A16 + (size_t)(m0 + row) * 1024 + k0 + sc8);
      }
    } else {
      const float* A32 = (const float*)Ap;
#pragma unroll
      for (int p = 0; p < 4; ++p) {
        int row = srow + 32 * p;
        const float* src = A32 + (size_t)(m0 + row) * 1024 + k0 + sc8;
        float4 u = *(const float4*)src;
        float4 v = *(const float4*)(src + 4);
        f16x8 h;
        h[0] = (__fp16)u.x; h[1] = (__fp16)u.y;
        h[2] = (__fp16)u.z; h[3] = (__fp16)u.w;
        h[4] = (__fp16)v.x; h[5] = (__fp16)v.y;
        h[6] = (__fp16)v.z; h[7] = (__fp16)v.w;
        *(f16x8*)&As[row][sc8] = h;
      }
    }
    // ---- B staging ----
    if (MODE == 2) {
      const float* B32 = (const float*)Bp;  // Wv row-major [k][1024]
#pragma unroll
      for (int p = 0; p < 2; ++p) {
        int kc = gk0 + 32 * p;
        f16x8 h;
#pragma unroll
        for (int j = 0; j < 8; ++j)
          h[j] = (__fp16)B32[(size_t)(k0 + kc + j) * 1024 + n0 + gn_];
        *(f16x8*)&Bs[gn_][kc] = h;
      }
    } else {
      const __half* B16 = (const __half*)Bp;  // WT [n][k]
      if (srow < 32) {
#pragma unroll
        for (int p = 0; p < 2; ++p) {
          int row = srow + 32 * p;
          *(f16x8*)&Bs[row][sc8] =
              *(const f16x8*)(B16 + (size_t)(n0 + row) * 1024 + k0 + sc8);
        }
      }
    }
    __syncthreads();
    // ---- MFMA ----
#pragma unroll
    for (int ks = 0; ks < 2; ++ks) {
      f16x8 af[2], bf[4];
#pragma unroll
      for (int mt = 0; mt < 2; ++mt)
        af[mt] = *(const f16x8*)&As[wm + mt * 16 + lqi][ks * 32 + quad * 8];
#pragma unroll
      for (int nt = 0; nt < 4; ++nt)
        bf[nt] = *(const f16x8*)&Bs[nt * 16 + lqi][ks * 32 + quad * 8];
#pragma unroll
      for (int mt = 0; mt < 2; ++mt)
#pragma unroll
        for (int nt = 0; nt < 4; ++nt)
          acc[mt][nt] = __builtin_amdgcn_mfma_f32_16x16x32_f16(
              af[mt], bf[nt], acc[mt][nt], 0, 0, 0);
    }
  }

  // ---- epilogue ----
  const int b = m0 >> 11;
  const int s0 = (m0 & 2047) + wm + quad * 4;
  if (MODE == 0 || MODE == 1) {
    __half* dst = (__half*)Cp;
    const int comp = n0 >> 10, hh = (n0 >> 6) & 15;
    __half* base = dst + ((size_t)(b * 2 + comp) * NH + hh) * (size_t)S_LEN * HD;
#pragma unroll
    for (int nt = 0; nt < 2; ++nt) {
      int p = nt * 16 + lqi;
#pragma unroll
      for (int mt = 0; mt < 2; ++mt) {
#pragma unroll
        for (int i = 0; i < 4; ++i) {
          int s = s0 + mt * 16 + i;
          float2 cs = tab[s * 32 + p];
          float x1 = acc[mt][nt][i], x2 = acc[mt][nt + 2][i];
          float y1 = x1 * cs.x - x2 * cs.y;
          float y2 = x2 * cs.x + x1 * cs.y;
          if (MODE == 1) { y1 *= SCALE_LOG2E; y2 *= SCALE_LOG2E; }
          base[(size_t)s * HD + p] = __float2half(y1);
          base[(size_t)s * HD + p + 32] = __float2half(y2);
        }
      }
    }
  } else if (MODE == 2) {
    __half* vt = (__half*)Cp;
    const int hh = n0 >> 6;
#pragma unroll
    for (int nt = 0; nt < 4; ++nt) {
      int hd = nt * 16 + lqi;
      __half* base = vt + (((size_t)b * NH + hh) * HD + hd) * S_LEN;
#pragma unroll
      for (int mt = 0; mt < 2; ++mt) {
        f16x4 hv;
#pragma unroll
        for (int i = 0; i < 4; ++i) hv[i] = (__fp16)acc[mt][nt][i];
        *(f16x4*)(base + s0 + mt * 16) = hv;
      }
    }
  } else {
    float* Co = (float*)Cp;
#pragma unroll
    for (int mt = 0; mt < 2; ++mt)
#pragma unroll
      for (int i = 0; i < 4; ++i) {
        int m = m0 + wm + mt * 16 + quad * 4 + i;
#pragma unroll
        for (int nt = 0; nt < 4; ++nt)
          Co[(size_t)m * 1024 + n0 + nt * 16 + lqi] = acc[mt][nt][i];
      }
  }
}

// ---------------------------------------------------------------------------
// Differential attention, R13: ASYNC global->LDS STAGING on the R9 shape.
// Evidence chain: 108.5us invariant across R7/R9 inner-loop designs; R12
// (2x waves) showed wall responds ADDITIVELY to per-wave overhead (Δwall ~
// ΔLDS-traffic) -> revert to 4 waves x 32q.  Remaining suspect for the
// ~5200 unaccounted cyc/kt: the staging chain global->r[6](24 VGPR held)->
// vmcnt(0)->ds_write, where the compiler's register-pressure motive sinks
// loads toward use, exposing ~900cyc HBM latency every kt -- a fixed cost
// matching the 108.5 invariance.  Fix: __builtin_amdgcn_global_load_lds
// width=16 (fire-and-forget; cannot be sunk; no VGPR round-trip; ds_writes
// deleted).  K dst is already wave-uniform-base + lane*16B; V keeps a
// LINEAR LDS dst with the XOR swizzle moved into the per-lane GLOBAL source
// address (read-side swizzle unchanged).  One barrier/kt; register-P x32 PV
// via custom key enumeration; scale folded into q.  LDS 48KB, 2 blocks/CU.
// ---------------------------------------------------------------------------
__global__ __launch_bounds__(256, 2) void attn_kernel(
    const __half* __restrict__ q_h, const __half* __restrict__ k_h,
    const __half* __restrict__ vt_h, float* __restrict__ out,
    const float* __restrict__ lq1, const float* __restrict__ lk1,
    const float* __restrict__ lq2, const float* __restrict__ lk2,
    const float* __restrict__ lam_init_p) {
  // K: 16 chunks x 512 halves, chunk = str*8 + mt*2 + ks, addr lane*8.
  // V: [hd 0..63][key 0..63], XOR-swizzled 16B slots within each 128B row
  //    (swizzle applied via the global source address; LDS write is linear).
  __shared__ __half Ks[2][16][512];      // 32 KB
  __shared__ __half Vs[2][64][64];       // 16 KB

  const int t = threadIdx.x;
  const int w = t >> 6, lane = t & 63;
  const int quad = lane >> 4, lqi = lane & 15;
  const int r7 = lane & 7;
  const int qt = blockIdx.x;   // 0..15 (128-query tiles)
  const int bh = blockIdx.y;   // 0..31
  const int b = bh >> 4, h = bh & 15;

  const size_t c1 = ((size_t)(b * 2 + 0) * NH + h) * (size_t)S_LEN * HD;
  const size_t c2 = ((size_t)(b * 2 + 1) * NH + h) * (size_t)S_LEN * HD;
  const size_t vtb = ((size_t)b * NH + h) * (size_t)HD * S_LEN;
  const int q0 = qt * 128 + w * 32;

  f16x8 qf[2][2][2];  // [stream][nt][ks]; q pre-scaled by SCALE_LOG2E
#pragma unroll
  for (int nt = 0; nt < 2; ++nt)
#pragma unroll
    for (int ks = 0; ks < 2; ++ks) {
      size_t a = (size_t)(q0 + nt * 16 + lqi) * HD + ks * 32 + quad * 8;
      qf[0][nt][ks] = *(const f16x8*)(q_h + c1 + a);
      qf[1][nt][ks] = *(const f16x8*)(q_h + c2 + a);
    }

  f32x4 O[2][4][2];  // [stream][hd-chunk][nt]
#pragma unroll
  for (int s = 0; s < 2; ++s)
#pragma unroll
    for (int hm = 0; hm < 4; ++hm)
#pragma unroll
      for (int nt = 0; nt < 2; ++nt) O[s][hm][nt] = (f32x4){0.f, 0.f, 0.f, 0.f};
  float lsum[2][2] = {{0.f, 0.f}, {0.f, 0.f}};

  // async staging: 24 chunks (16 K + 8 V); wave w owns c = w + ci*4.
  // LDS dest is wave-uniform base (HW adds lane*16B); global src is per-lane.
  auto stage = [&](int c, int k0, int buf) {
    const __half* src;
    __half* dst;
    if (c < 16) {
      int str = c >> 3, mt = (c >> 1) & 3, ks = c & 1;
      src = k_h + (str ? c2 : c1) + (size_t)(k0 + mt * 16 + lqi) * HD +
            ks * 32 + quad * 8;
      dst = &Ks[buf][c][0];
    } else {
      int cc = c - 16;  // V chunk: rows [cc*8, cc*8+8), 64 keys
      // pre-swizzled global source: lane L fills linear slot (L&7) of row
      // cc*8+(L>>3) with key-slot (L&7)^(L>>3)  => content at (row,slot)
      // has key-slot slot^(row&7), matching the read-side XOR.
      src = vt_h + vtb + (size_t)(cc * 8 + (lane >> 3)) * S_LEN + k0 +
            ((lane & 7) ^ (lane >> 3)) * 8;
      dst = &Vs[buf][cc * 8][0];
    }
    __builtin_amdgcn_global_load_lds(
        (const __attribute__((address_space(1))) unsigned int*)(const void*)src,
        (__attribute__((address_space(3))) unsigned int*)(void*)dst, 16, 0, 0);
  };

  // prologue: stage tile 0 into buffer 0
#pragma unroll
  for (int ci = 0; ci < 6; ++ci) stage(w + ci * 4, 0, 0);
  __syncthreads();

  for (int kt = 0; kt < 32; ++kt) {
    const int cur = kt & 1;
    if (kt < 31) {  // fire-and-forget async loads for tile kt+1
#pragma unroll
      for (int ci = 0; ci < 6; ++ci) stage(w + ci * 4, (kt + 1) * 64, cur ^ 1);
    }

#pragma unroll
    for (int g = 0; g < 2; ++g) {  // 32-key groups (score tiles 2g, 2g+1)
      // ---- V fragments in permuted key order (2 b64 each, swizzle-read) ---
      f16x8 vf[4];
#pragma unroll
      for (int hm = 0; hm < 4; ++hm) {
        const __half* vrow = &Vs[cur][hm * 16 + lqi][0];
        int s0 = (g * 4 + (quad >> 1)) ^ r7;      // keys g*32 + quad*4 ..
        int s1 = (g * 4 + 2 + (quad >> 1)) ^ r7;  // keys g*32+16 + quad*4 ..
        union { f16x8 v8; f16x4 v4[2]; } u;
        u.v4[0] = *(const f16x4*)(vrow + s0 * 8 + (quad & 1) * 4);
        u.v4[1] = *(const f16x4*)(vrow + s1 * 8 + (quad & 1) * 4);
        vf[hm] = u.v8;
      }
      // ---- scores + exp for tiles 2g and 2g+1; B-frag stays in-lane ----
      f16x8 bfrag[2][2];
#pragma unroll
      for (int str = 0; str < 2; ++str) {
        f16x8 kf00 = *(const f16x8*)&Ks[cur][str * 8 + g * 4 + 0][lane * 8];
        f16x8 kf01 = *(const f16x8*)&Ks[cur][str * 8 + g * 4 + 1][lane * 8];
        f16x8 kf10 = *(const f16x8*)&Ks[cur][str * 8 + g * 4 + 2][lane * 8];
        f16x8 kf11 = *(const f16x8*)&Ks[cur][str * 8 + g * 4 + 3][lane * 8];
#pragma unroll
        for (int nt = 0; nt < 2; ++nt) {
          f32x4 sa = (f32x4){0.f, 0.f, 0.f, 0.f};
          f32x4 sb = (f32x4){0.f, 0.f, 0.f, 0.f};
          sa = __builtin_amdgcn_mfma_f32_16x16x32_f16(kf00, qf[str][nt][0], sa,
                                                      0, 0, 0);
          sa = __builtin_amdgcn_mfma_f32_16x16x32_f16(kf01, qf[str][nt][1], sa,
                                                      0, 0, 0);
          sb = __builtin_amdgcn_mfma_f32_16x16x32_f16(kf10, qf[str][nt][0], sb,
                                                      0, 0, 0);
          sb = __builtin_amdgcn_mfma_f32_16x16x32_f16(kf11, qf[str][nt][1], sb,
                                                      0, 0, 0);
          float ea0 = __builtin_amdgcn_exp2f(sa[0]);
          float ea1 = __builtin_amdgcn_exp2f(sa[1]);
          float ea2 = __builtin_amdgcn_exp2f(sa[2]);
          float ea3 = __builtin_amdgcn_exp2f(sa[3]);
          float eb0 = __builtin_amdgcn_exp2f(sb[0]);
          float eb1 = __builtin_amdgcn_exp2f(sb[1]);
          float eb2 = __builtin_amdgcn_exp2f(sb[2]);
          float eb3 = __builtin_amdgcn_exp2f(sb[3]);
          lsum[str][nt] += ((ea0 + ea1) + (ea2 + ea3)) +
                           ((eb0 + eb1) + (eb2 + eb3));
          union { f16x8 v; f16x2 h2[4]; } pu;
          pu.h2[0] = __builtin_amdgcn_cvt_pkrtz(ea0, ea1);
          pu.h2[1] = __builtin_amdgcn_cvt_pkrtz(ea2, ea3);
          pu.h2[2] = __builtin_amdgcn_cvt_pkrtz(eb0, eb1);
          pu.h2[3] = __builtin_amdgcn_cvt_pkrtz(eb2, eb3);
          bfrag[str][nt] = pu.v;
        }
      }
      // ---- PV: full-rate x32 MFMAs, P fragment straight from registers ----
#pragma unroll
      for (int hm = 0; hm < 4; ++hm)
#pragma unroll
        for (int str = 0; str < 2; ++str)
#pragma unroll
          for (int nt = 0; nt < 2; ++nt)
            O[str][hm][nt] = __builtin_amdgcn_mfma_f32_16x16x32_f16(
                vf[hm], bfrag[str][nt], O[str][hm][nt], 0, 0, 0);
    }

    if (kt < 31) __syncthreads();  // drains vmcnt -> tile kt+1 visible
  }

  const float lam0 = lam_init_p[0];
  const float lam = expf(lq1[h] * lk1[h]) - expf(lq2[h] * lk2[h]) + lam0;
#pragma unroll
  for (int str = 0; str < 2; ++str)
#pragma unroll
    for (int nt = 0; nt < 2; ++nt) {
      float v = lsum[str][nt];
      v += __shfl_xor(v, 16);
      v += __shfl_xor(v, 32);
      lsum[str][nt] = v;
    }
#pragma unroll
  for (int nt = 0; nt < 2; ++nt) {
    float il1 = 1.f / lsum[0][nt];
    float il2 = lam / lsum[1][nt];
    int q = q0 + nt * 16 + lqi;
#pragma unroll
    for (int hm = 0; hm < 4; ++hm) {
      f32x4 o;
#pragma unroll
      for (int i = 0; i < 4; ++i)
        o[i] = O[0][hm][nt][i] * il1 - O[1][hm][nt][i] * il2;
      *(f32x4*)(out + ((size_t)(b * S_LEN + q)) * THD_ + h * HD + hm * 16 +
                quad * 4) = o;
    }
  }
}

// ---------------------------------------------------------------------------
// Fused GroupNorm + Wo transpose. Blocks [0,16384): GroupNorm over 64-elem
// head groups (d_out fp32 -> gn_h fp16, * (1-lambda_init)); blocks
// [16384,16896): transpose Wo fp32 -> WoT fp16 [n][k].
// ---------------------------------------------------------------------------
__global__ __launch_bounds__(256) void gn_wt_kernel(
    const float* __restrict__ src, __half* __restrict__ dst,
    const float* __restrict__ gw, const float* __restrict__ gb,
    const float* __restrict__ lam_init_p, const float* __restrict__ Wo,
    __half* __restrict__ WoT) {
  if (blockIdx.x >= 16384) {
    wt_body(Wo, WoT, (blockIdx.x - 16384) * 256 + threadIdx.x, 1023, 10);
    return;
  }
  int g = blockIdx.x * 4 + (threadIdx.x >> 6);
  int lane = threadIdx.x & 63;
  float v = src[(size_t)g * 64 + lane];
  float s = v, sq = v * v;
#pragma unroll
  for (int off = 32; off; off >>= 1) {
    s += __shfl_xor(s, off);
    sq += __shfl_xor(sq, off);
  }
  float mean = s * (1.f / 64.f);
  float var = sq * (1.f / 64.f) - mean * mean;
  float rs = rsqrtf(var + 1e-5f);
  int h = g & 15;
  float w = gw[h * 64 + lane], bb = gb[h * 64 + lane];
  dst[(size_t)g * 64 + lane] =
      __float2half(((v - mean) * rs * w + bb) * (1.f - lam_init_p[0]));
}

// ---------------------------------------------------------------------------
extern "C" void kernel_launch(void* const* d_in, const int* in_sizes, int n_in,
                              void* d_out, int out_size, void* d_ws,
                              size_t ws_size, hipStream_t stream) {
  const float* x = (const float*)d_in[0];
  const float* Wq = (const float*)d_in[1];
  const float* Wk = (const float*)d_in[2];
  const float* Wv = (const float*)d_in[3];
  const float* Wo = (const float*)d_in[4];
  const float* lq1 = (const float*)d_in[5];
  const float* lk1 = (const float*)d_in[6];
  const float* lq2 = (const float*)d_in[7];
  const float* lk2 = (const float*)d_in[8];
  const float* lam_init = (const float*)d_in[9];
  const float* gnw = (const float*)d_in[10];
  const float* gnb = (const float*)d_in[11];
  float* out = (float*)d_out;

  __half* q_h = (__half*)d_ws;          // region A
  __half* k_h = q_h + 8388608;          // region B
  __half* vt_h = k_h + 8388608;         // region C
  __half* WqT = k_h;                    // B[0:2097152)  (dead after q-GEMM)
  __half* WkT = vt_h;                   // C[0:2097152)  (dead after k-GEMM)
  float2* tab = (float2*)(vt_h + 2097152);  // C[2097152:2359296) fp32 pairs
  __half* WoT = q_h;                    // A[0:1048576)  (q dead after attn)
  __half* gn_h = q_h + 1048576;         // A[1048576:5242880)

  dim3 blk(256);
  // fused prep: Wq/Wk transposes + rope table (1 dispatch)
  prep_kernel<<<2304, blk, 0, stream>>>(Wq, Wk, WqT, WkT, tab);
  // projections (64-wide tiles, R6 proven config); MODE 1 folds scale*log2e
  mfma_gemm<1><<<dim3(32, 32), blk, 0, stream>>>(x, WqT, q_h, tab);
  mfma_gemm<0><<<dim3(32, 32), blk, 0, stream>>>(x, WkT, k_h, tab);
  mfma_gemm<2><<<dim3(16, 32), blk, 0, stream>>>(x, Wv, vt_h, nullptr);
  // differential attention -> d_out (R13: async global->LDS staging)
  attn_kernel<<<dim3(16, 32), blk, 0, stream>>>(q_h, k_h, vt_h, out, lq1, lk1,
                                                lq2, lk2, lam_init);
  // fused GroupNorm + Wo transpose (1 dispatch)
  gn_wt_kernel<<<16896, blk, 0, stream>>>(out, gn_h, gnw, gnb, lam_init, Wo,
                                          WoT);
  // output projection: gn_h @ WoT -> d_out
  mfma_gemm<3><<<dim3(16, 32), blk, 0, stream>>>(gn_h, WoT, out, nullptr);
}